// Round 1
// baseline (773.605 us; speedup 1.0000x reference)
//
#include <hip/hip_runtime.h>
#include <hip/hip_bf16.h>

// Conv2D valid cross-correlation: x(64,1024,1024) fp32 * k(16,16) fp32 -> out(64,1009,1009) fp32.
// Block: 256 thr = 64(W) x 4(H). Thread tile: 8 rows x 4 cols.
// Block tile: 32 rows x 256 cols. LDS patch: 47 x 272 fp32 (51 KB) -> 3 blocks/CU.
// Wave spans W only => kernel row index ki is wave-uniform => scalar (s_load) taps.

#define CONV_B  64
#define CONV_H  1024
#define CONV_W  1024
#define CONV_KH 16
#define CONV_KW 16
#define CONV_OH 1009
#define CONV_OW 1009

#define TILE_H   32          // output rows per block
#define TILE_W   256         // output cols per block
#define TH       8           // output rows per thread
#define TW       4           // output cols per thread
#define LDS_ROWS (TILE_H + 15)   // 47
#define LDS_COLS 272             // 271 needed, pad to x4 for float4 alignment

__global__ __launch_bounds__(256)
void conv2d_direct_f32(const float* __restrict__ x,
                       const float* __restrict__ kern,
                       float* __restrict__ out) {
    __shared__ float lds[LDS_ROWS * LDS_COLS];

    const int tid = threadIdx.x;
    const int tx = tid & 63;        // 0..63 along W
    const int ty = tid >> 6;        // 0..3 along H (one wave per ty)
    const int b  = blockIdx.z;
    const int i0 = blockIdx.y * TILE_H;   // output row base of block
    const int j0 = blockIdx.x * TILE_W;   // output col base of block

    // ---- Stage input patch (47 x 271 used cols) into LDS, float4 where possible ----
    // Patch covers input rows i0..i0+46, cols j0..j0+270.
    for (int idx4 = tid; idx4 < LDS_ROWS * (LDS_COLS / 4); idx4 += 256) {
        const int r  = idx4 / (LDS_COLS / 4);
        const int c4 = (idx4 - r * (LDS_COLS / 4)) * 4;
        const int gr = i0 + r;
        const int gc = j0 + c4;
        float4 v = make_float4(0.f, 0.f, 0.f, 0.f);
        if (gr < CONV_H) {
            if (gc + 3 < CONV_W) {
                v = *(const float4*)(x + ((size_t)b * CONV_H + gr) * CONV_W + gc);
            } else {
                const float* row = x + ((size_t)b * CONV_H + gr) * CONV_W;
                float t[4];
                #pragma unroll
                for (int t_i = 0; t_i < 4; ++t_i)
                    t[t_i] = (gc + t_i < CONV_W) ? row[gc + t_i] : 0.f;
                v = make_float4(t[0], t[1], t[2], t[3]);
            }
        }
        *(float4*)(&lds[r * LDS_COLS + c4]) = v;
    }
    __syncthreads();

    // ---- Compute: 8x4 outputs per thread ----
    const int i0t = ty * TH;     // thread's row base within tile
    const int j0t = tx * TW;     // thread's col base within tile

    float acc[TH][TW];
    #pragma unroll
    for (int ii = 0; ii < TH; ++ii)
        #pragma unroll
        for (int jj = 0; jj < TW; ++jj) acc[ii][jj] = 0.f;

    // Loop over the 23 input rows this thread touches: rr = row - i0t in [0,22].
    for (int rr = 0; rr < TH + 15; ++rr) {
        const float* lrow = &lds[(i0t + rr) * LDS_COLS + j0t];
        float xr[TW + 15];                 // 19 floats, ds_read_b128-merged
        #pragma unroll
        for (int t = 0; t < TW + 15; ++t) xr[t] = lrow[t];

        #pragma unroll
        for (int ii = 0; ii < TH; ++ii) {
            const int ki = rr - ii;        // wave-uniform (rr uniform, ii static)
            if (ki >= 0 && ki < CONV_KH) {
                const float* krow = kern + ki * CONV_KW;   // uniform -> s_load
                #pragma unroll
                for (int kj = 0; kj < CONV_KW; ++kj) {
                    const float kv = krow[kj];
                    #pragma unroll
                    for (int jj = 0; jj < TW; ++jj)
                        acc[ii][jj] = fmaf(kv, xr[kj + jj], acc[ii][jj]);
                }
            }
        }
    }

    // ---- Store (guarded; L2 merges the stride-16B lane pattern) ----
    #pragma unroll
    for (int ii = 0; ii < TH; ++ii) {
        const int gi = i0 + i0t + ii;
        if (gi < CONV_OH) {
            float* orow = out + ((size_t)b * CONV_OH + gi) * CONV_OW;
            #pragma unroll
            for (int jj = 0; jj < TW; ++jj) {
                const int gj = j0 + j0t + jj;
                if (gj < CONV_OW) orow[gj] = acc[ii][jj];
            }
        }
    }
}

extern "C" void kernel_launch(void* const* d_in, const int* in_sizes, int n_in,
                              void* d_out, int out_size, void* d_ws, size_t ws_size,
                              hipStream_t stream) {
    const float* x    = (const float*)d_in[0];
    const float* kern = (const float*)d_in[1];
    float* out        = (float*)d_out;

    dim3 grid((CONV_OW + TILE_W - 1) / TILE_W,    // 4
              (CONV_OH + TILE_H - 1) / TILE_H,    // 32
              CONV_B);                            // 64
    dim3 block(256);
    conv2d_direct_f32<<<grid, block, 0, stream>>>(x, kern, out);
}